// Round 1
// baseline (448.495 us; speedup 1.0000x reference)
//
#include <hip/hip_runtime.h>

// ---------------------------------------------------------------------------
// GNN: 2x SAGEConv(mean) + ReLU, global mean pool, 2-layer MLP classifier.
// N=50000 nodes, E=600000 edges, F=H=128, 64 graphs. All fp32.
// ---------------------------------------------------------------------------

// ---- CSR build ------------------------------------------------------------

__global__ __launch_bounds__(256) void k_deg(const int* __restrict__ ei, int* __restrict__ cnt, int E) {
  int e = blockIdx.x * 256 + threadIdx.x;
  if (e < E) atomicAdd(&cnt[ei[E + e]], 1);  // dst = ei[E+e]
}

__global__ __launch_bounds__(1024) void k_scan(int* __restrict__ cnt, int* __restrict__ off,
                                               int n) {
  // single-block exclusive scan over cnt[n] -> off[n+1]; also resets cnt[i] = off[i]
  // (cnt doubles as the fill cursor afterwards)
  __shared__ int s[1024];
  int t = threadIdx.x;
  int per = (n + 1023) >> 10;
  int st = t * per;
  int en = min(st + per, n);
  int sum = 0;
  for (int i = st; i < en; ++i) sum += cnt[i];
  s[t] = sum;
  __syncthreads();
  for (int d = 1; d < 1024; d <<= 1) {
    int v = (t >= d) ? s[t - d] : 0;
    __syncthreads();
    s[t] += v;
    __syncthreads();
  }
  int run = (t == 0) ? 0 : s[t - 1];
  int total = s[1023];
  for (int i = st; i < en; ++i) {
    int c = cnt[i];          // read BEFORE overwriting (cnt aliases cursor)
    off[i] = run;
    cnt[i] = run;            // cursor init
    run += c;
  }
  if (t == 0) off[n] = total;
}

__global__ __launch_bounds__(256) void k_fill(const int* __restrict__ ei, int* __restrict__ cursor,
                                              int* __restrict__ col, int E) {
  int e = blockIdx.x * 256 + threadIdx.x;
  if (e < E) {
    int d = ei[E + e];
    int p = atomicAdd(&cursor[d], 1);
    col[p] = ei[e];          // src
  }
}

// ---- mean aggregation: T[i,:] = mean_{j in N(i)} X[j,:] -------------------

__global__ __launch_bounds__(256) void k_agg(const float* __restrict__ X, const int* __restrict__ off,
                                             const int* __restrict__ col, float* __restrict__ T, int N) {
  int wid = (blockIdx.x * 256 + threadIdx.x) >> 6;  // one wave per node
  int lane = threadIdx.x & 63;
  if (wid >= N) return;
  int o0 = off[wid], o1 = off[wid + 1];
  int deg = o1 - o0;
  float ax = 0.f, ay = 0.f;
  for (int base = 0; base < deg; base += 64) {
    int cnt = min(64, deg - base);
    int cv = (lane < cnt) ? col[o0 + base + lane] : 0;
    int i = 0;
    for (; i + 4 <= cnt; i += 4) {
      int s0 = __shfl(cv, i), s1 = __shfl(cv, i + 1), s2 = __shfl(cv, i + 2), s3 = __shfl(cv, i + 3);
      float2 v0 = *(const float2*)(X + (size_t)s0 * 128 + lane * 2);
      float2 v1 = *(const float2*)(X + (size_t)s1 * 128 + lane * 2);
      float2 v2 = *(const float2*)(X + (size_t)s2 * 128 + lane * 2);
      float2 v3 = *(const float2*)(X + (size_t)s3 * 128 + lane * 2);
      ax += v0.x + v1.x + v2.x + v3.x;
      ay += v0.y + v1.y + v2.y + v3.y;
    }
    for (; i < cnt; ++i) {
      int s0 = __shfl(cv, i);
      float2 v0 = *(const float2*)(X + (size_t)s0 * 128 + lane * 2);
      ax += v0.x;
      ay += v0.y;
    }
  }
  float sc = 1.0f / (float)max(deg, 1);
  float2 r;
  r.x = ax * sc;
  r.y = ay * sc;
  *(float2*)(T + (size_t)wid * 128 + lane * 2) = r;
}

// ---- fused linear: OUT = relu(A @ Wl.T + X @ Wr.T + b) --------------------
// A,X: [N,128]; Wl,Wr: [128,128] row-major; OUT: [N,128]
// Tile: 64 nodes x 128 outputs per block (256 threads), 4x8 acc per thread.
// NOTE: A and OUT may alias (each block reads only its own rows before write).

__global__ __launch_bounds__(256) void k_lin(const float* A, const float* __restrict__ X,
                                             const float* __restrict__ Wl, const float* __restrict__ Wr,
                                             const float* __restrict__ bias, float* OUT,
                                             int N, int relu) {
  __shared__ float As[64][36];    // [node][k] padded
  __shared__ float Ws[32][132];   // [k][h] transposed, padded
  int tid = threadIdx.x;
  int tx = tid & 15;              // h group: h0 = tx*8
  int ty = tid >> 4;              // node group: n0 = ty*4
  int rowBase = blockIdx.x * 64;
  float acc[4][8];
#pragma unroll
  for (int i = 0; i < 4; ++i)
#pragma unroll
    for (int j = 0; j < 8; ++j) acc[i][j] = 0.f;

  for (int c = 0; c < 8; ++c) {
    const float* S = (c < 4) ? A : X;
    const float* W = (c < 4) ? Wl : Wr;
    int kOff = (c & 3) * 32;
    __syncthreads();
    // stage A chunk: 64 rows x 32 k
#pragma unroll
    for (int n = 0; n < 2; ++n) {
      int idx = tid + n * 256;
      int r = idx >> 3, q = idx & 7;
      int gr = min(rowBase + r, N - 1);
      const float4 v = *(const float4*)(S + (size_t)gr * 128 + kOff + q * 4);
      *(float4*)(&As[r][q * 4]) = v;
    }
    // stage W chunk transposed: Ws[k][h] = W[h][kOff+k]
#pragma unroll
    for (int n = 0; n < 4; ++n) {
      int idx = tid + n * 256;
      int h = idx >> 3, q = idx & 7;
      const float4 v = *(const float4*)(W + (size_t)h * 128 + kOff + q * 4);
      Ws[q * 4 + 0][h] = v.x;
      Ws[q * 4 + 1][h] = v.y;
      Ws[q * 4 + 2][h] = v.z;
      Ws[q * 4 + 3][h] = v.w;
    }
    __syncthreads();
#pragma unroll
    for (int kk = 0; kk < 32; ++kk) {
      float a[4];
#pragma unroll
      for (int i = 0; i < 4; ++i) a[i] = As[ty * 4 + i][kk];
      const float4 w0 = *(const float4*)(&Ws[kk][tx * 8]);
      const float4 w1 = *(const float4*)(&Ws[kk][tx * 8 + 4]);
      float w[8] = {w0.x, w0.y, w0.z, w0.w, w1.x, w1.y, w1.z, w1.w};
#pragma unroll
      for (int i = 0; i < 4; ++i)
#pragma unroll
        for (int j = 0; j < 8; ++j) acc[i][j] += a[i] * w[j];
    }
  }
#pragma unroll
  for (int i = 0; i < 4; ++i) {
    int row = rowBase + ty * 4 + i;
    if (row < N) {
      int h0 = tx * 8;
      float4 r0, r1;
      r0.x = acc[i][0] + bias[h0 + 0];
      r0.y = acc[i][1] + bias[h0 + 1];
      r0.z = acc[i][2] + bias[h0 + 2];
      r0.w = acc[i][3] + bias[h0 + 3];
      r1.x = acc[i][4] + bias[h0 + 4];
      r1.y = acc[i][5] + bias[h0 + 5];
      r1.z = acc[i][6] + bias[h0 + 6];
      r1.w = acc[i][7] + bias[h0 + 7];
      if (relu) {
        r0.x = fmaxf(r0.x, 0.f); r0.y = fmaxf(r0.y, 0.f); r0.z = fmaxf(r0.z, 0.f); r0.w = fmaxf(r0.w, 0.f);
        r1.x = fmaxf(r1.x, 0.f); r1.y = fmaxf(r1.y, 0.f); r1.z = fmaxf(r1.z, 0.f); r1.w = fmaxf(r1.w, 0.f);
      }
      *(float4*)(OUT + (size_t)row * 128 + h0) = r0;
      *(float4*)(OUT + (size_t)row * 128 + h0 + 4) = r1;
    }
  }
}

// ---- global mean pool (batch is sorted) -----------------------------------

#define POOL_NODES 256
__global__ __launch_bounds__(128) void k_pool(const float* __restrict__ H, const int* __restrict__ batch,
                                              float* __restrict__ gsum, int* __restrict__ gcnt, int N) {
  int f = threadIdx.x;  // feature
  int start = blockIdx.x * POOL_NODES;
  int end = min(start + POOL_NODES, N);
  if (start >= N) return;
  float acc = 0.f;
  int curg = batch[start];
  int run = 0;
  for (int i = start; i < end; ++i) {
    int g = batch[i];
    if (g != curg) {
      atomicAdd(&gsum[curg * 128 + f], acc);
      if (f == 0) atomicAdd(&gcnt[curg], run);
      acc = 0.f;
      run = 0;
      curg = g;
    }
    acc += H[(size_t)i * 128 + f];
    run++;
  }
  atomicAdd(&gsum[curg * 128 + f], acc);
  if (f == 0) atomicAdd(&gcnt[curg], run);
}

// ---- classifier -----------------------------------------------------------

__global__ __launch_bounds__(128) void k_cls1(const float* __restrict__ gsum, const int* __restrict__ gcnt,
                                              const float* __restrict__ Wc1, const float* __restrict__ bc1,
                                              float* __restrict__ z) {
  int g = blockIdx.x;   // 64 graphs
  int h = threadIdx.x;  // 128 hidden
  float inv = 1.0f / (float)max(gcnt[g], 1);
  float s = 0.f;
  for (int f = 0; f < 128; ++f) s += gsum[g * 128 + f] * Wc1[h * 128 + f];
  z[g * 128 + h] = fmaxf(s * inv + bc1[h], 0.f);
}

__global__ __launch_bounds__(128) void k_cls2(const float* __restrict__ z, const float* __restrict__ Wc2,
                                              const float* __restrict__ bc2, float* __restrict__ out) {
  __shared__ float red[128];
  int g = blockIdx.x;
  int t = threadIdx.x;
  red[t] = z[g * 128 + t] * Wc2[t];
  __syncthreads();
  for (int d = 64; d > 0; d >>= 1) {
    if (t < d) red[t] += red[t + d];
    __syncthreads();
  }
  if (t == 0) out[g] = red[0] + bc2[0];
}

// ---------------------------------------------------------------------------

extern "C" void kernel_launch(void* const* d_in, const int* in_sizes, int n_in,
                              void* d_out, int out_size, void* d_ws, size_t ws_size,
                              hipStream_t stream) {
  const float* x   = (const float*)d_in[0];
  const int*   ei  = (const int*)d_in[1];
  const int*   bat = (const int*)d_in[2];
  const float* W1l = (const float*)d_in[3];
  const float* b1l = (const float*)d_in[4];
  const float* W1r = (const float*)d_in[5];
  const float* W2l = (const float*)d_in[6];
  const float* b2l = (const float*)d_in[7];
  const float* W2r = (const float*)d_in[8];
  const float* Wc1 = (const float*)d_in[9];
  const float* bc1 = (const float*)d_in[10];
  const float* Wc2 = (const float*)d_in[11];
  const float* bc2 = (const float*)d_in[12];
  float* out = (float*)d_out;

  int N = in_sizes[0] / 128;
  int E = in_sizes[1] / 2;

  char* ws = (char*)d_ws;
  size_t o = 0;
  auto alloc = [&](size_t bytes) {
    char* p = ws + o;
    o += (bytes + 255) & ~(size_t)255;
    return p;
  };
  int*   cursor = (int*)alloc((size_t)N * 4);            // deg counter, then fill cursor
  int*   off    = (int*)alloc((size_t)(N + 1) * 4);
  int*   col    = (int*)alloc((size_t)E * 4);
  float* T      = (float*)alloc((size_t)N * 128 * 4);    // agg buffer; layer-2 out aliases it
  float* h1     = (float*)alloc((size_t)N * 128 * 4);
  float* gsum   = (float*)alloc(64 * 128 * 4 + 64 * 4);  // gsum + gcnt contiguous
  int*   gcnt   = (int*)(gsum + 64 * 128);
  float* z      = (float*)alloc(64 * 128 * 4);

  hipMemsetAsync(cursor, 0, (size_t)N * 4, stream);
  hipMemsetAsync(gsum, 0, 64 * 128 * 4 + 64 * 4, stream);

  k_deg<<<(E + 255) / 256, 256, 0, stream>>>(ei, cursor, E);
  k_scan<<<1, 1024, 0, stream>>>(cursor, off, N);
  k_fill<<<(E + 255) / 256, 256, 0, stream>>>(ei, cursor, col, E);

  // layer 1
  k_agg<<<(N + 3) / 4, 256, 0, stream>>>(x, off, col, T, N);
  k_lin<<<(N + 63) / 64, 256, 0, stream>>>(T, x, W1l, W1r, b1l, h1, N, 1);
  // layer 2 (output aliases T; per-block row ownership makes this safe)
  k_agg<<<(N + 3) / 4, 256, 0, stream>>>(h1, off, col, T, N);
  k_lin<<<(N + 63) / 64, 256, 0, stream>>>(T, h1, W2l, W2r, b2l, T, N, 1);

  // pooling + classifier
  k_pool<<<(N + POOL_NODES - 1) / POOL_NODES, 128, 0, stream>>>(T, bat, gsum, gcnt, N);
  k_cls1<<<64, 128, 0, stream>>>(gsum, gcnt, Wc1, bc1, z);
  k_cls2<<<64, 128, 0, stream>>>(z, Wc2, bc2, out);
}

// Round 2
// 353.845 us; speedup vs baseline: 1.2675x; 1.2675x over previous
//
#include <hip/hip_runtime.h>

// ---------------------------------------------------------------------------
// GNN: 2x SAGEConv(mean) + ReLU, global mean pool, 2-layer MLP classifier.
// N=50000 nodes, E=600000 edges, F=H=128, 64 graphs. All fp32.
// R2: replaced the single-block serial scan (110us, latency-bound) with a
//     3-stage hierarchical scan (~10us total).
// ---------------------------------------------------------------------------

// ---- CSR build ------------------------------------------------------------

__global__ __launch_bounds__(256) void k_deg(const int* __restrict__ ei, int* __restrict__ cnt, int E) {
  int e = blockIdx.x * 256 + threadIdx.x;
  if (e < E) atomicAdd(&cnt[ei[E + e]], 1);  // dst = ei[E+e]
}

// stage 1: per-block (1024 elems) local exclusive scan; block sums to bsum
__global__ __launch_bounds__(256) void k_scan_local(const int* __restrict__ cnt, int* __restrict__ off,
                                                    int* __restrict__ bsum, int n) {
  __shared__ int s[256];
  int t = threadIdx.x;
  int base = blockIdx.x * 1024 + t * 4;
  int v0 = 0, v1 = 0, v2 = 0, v3 = 0;
  if (base + 3 < n) {
    int4 q = *(const int4*)(cnt + base);
    v0 = q.x; v1 = q.y; v2 = q.z; v3 = q.w;
  } else {
    if (base + 0 < n) v0 = cnt[base + 0];
    if (base + 1 < n) v1 = cnt[base + 1];
    if (base + 2 < n) v2 = cnt[base + 2];
    if (base + 3 < n) v3 = cnt[base + 3];
  }
  s[t] = v0 + v1 + v2 + v3;
  __syncthreads();
  for (int d = 1; d < 256; d <<= 1) {
    int x = (t >= d) ? s[t - d] : 0;
    __syncthreads();
    s[t] += x;
    __syncthreads();
  }
  int pre = (t == 0) ? 0 : s[t - 1];
  if (t == 255) bsum[blockIdx.x] = s[255];
  int e0 = pre, e1 = e0 + v0, e2 = e1 + v1, e3 = e2 + v2;
  if (base + 3 < n) {
    *(int4*)(off + base) = make_int4(e0, e1, e2, e3);
  } else {
    if (base + 0 < n) off[base + 0] = e0;
    if (base + 1 < n) off[base + 1] = e1;
    if (base + 2 < n) off[base + 2] = e2;
    if (base + 3 < n) off[base + 3] = e3;
  }
}

// stage 2: scan the block sums (nb <= 256), write total to totalOut (=off[n])
__global__ __launch_bounds__(256) void k_scan_mid(int* __restrict__ bsum, int* __restrict__ totalOut, int nb) {
  __shared__ int s[256];
  int t = threadIdx.x;
  s[t] = (t < nb) ? bsum[t] : 0;
  __syncthreads();
  for (int d = 1; d < 256; d <<= 1) {
    int x = (t >= d) ? s[t - d] : 0;
    __syncthreads();
    s[t] += x;
    __syncthreads();
  }
  if (t < nb) bsum[t] = (t == 0) ? 0 : s[t - 1];
  if (t == 255) totalOut[0] = s[255];
}

// stage 3: add block prefix; also init fill cursor = off
__global__ __launch_bounds__(256) void k_scan_add(int* __restrict__ off, int* __restrict__ cursor,
                                                  const int* __restrict__ bsum, int n) {
  int base = blockIdx.x * 1024 + threadIdx.x * 4;
  int b = bsum[blockIdx.x];
  if (base + 3 < n) {
    int4 q = *(const int4*)(off + base);
    q.x += b; q.y += b; q.z += b; q.w += b;
    *(int4*)(off + base) = q;
    *(int4*)(cursor + base) = q;
  } else {
    for (int k = 0; k < 4; ++k)
      if (base + k < n) {
        int v = off[base + k] + b;
        off[base + k] = v;
        cursor[base + k] = v;
      }
  }
}

__global__ __launch_bounds__(256) void k_fill(const int* __restrict__ ei, int* __restrict__ cursor,
                                              int* __restrict__ col, int E) {
  int e = blockIdx.x * 256 + threadIdx.x;
  if (e < E) {
    int d = ei[E + e];
    int p = atomicAdd(&cursor[d], 1);
    col[p] = ei[e];          // src
  }
}

// ---- mean aggregation: T[i,:] = mean_{j in N(i)} X[j,:] -------------------

__global__ __launch_bounds__(256) void k_agg(const float* __restrict__ X, const int* __restrict__ off,
                                             const int* __restrict__ col, float* __restrict__ T, int N) {
  int wid = (blockIdx.x * 256 + threadIdx.x) >> 6;  // one wave per node
  int lane = threadIdx.x & 63;
  if (wid >= N) return;
  int o0 = off[wid], o1 = off[wid + 1];
  int deg = o1 - o0;
  float ax = 0.f, ay = 0.f;
  for (int base = 0; base < deg; base += 64) {
    int cnt = min(64, deg - base);
    int cv = (lane < cnt) ? col[o0 + base + lane] : 0;
    int i = 0;
    for (; i + 4 <= cnt; i += 4) {
      int s0 = __shfl(cv, i), s1 = __shfl(cv, i + 1), s2 = __shfl(cv, i + 2), s3 = __shfl(cv, i + 3);
      float2 v0 = *(const float2*)(X + (size_t)s0 * 128 + lane * 2);
      float2 v1 = *(const float2*)(X + (size_t)s1 * 128 + lane * 2);
      float2 v2 = *(const float2*)(X + (size_t)s2 * 128 + lane * 2);
      float2 v3 = *(const float2*)(X + (size_t)s3 * 128 + lane * 2);
      ax += v0.x + v1.x + v2.x + v3.x;
      ay += v0.y + v1.y + v2.y + v3.y;
    }
    for (; i < cnt; ++i) {
      int s0 = __shfl(cv, i);
      float2 v0 = *(const float2*)(X + (size_t)s0 * 128 + lane * 2);
      ax += v0.x;
      ay += v0.y;
    }
  }
  float sc = 1.0f / (float)max(deg, 1);
  float2 r;
  r.x = ax * sc;
  r.y = ay * sc;
  *(float2*)(T + (size_t)wid * 128 + lane * 2) = r;
}

// ---- fused linear: OUT = relu(A @ Wl.T + X @ Wr.T + b) --------------------
// A,X: [N,128]; Wl,Wr: [128,128] row-major; OUT: [N,128]
// Tile: 64 nodes x 128 outputs per block (256 threads), 4x8 acc per thread.
// NOTE: A and OUT may alias (each block reads only its own rows before write).

__global__ __launch_bounds__(256) void k_lin(const float* A, const float* __restrict__ X,
                                             const float* __restrict__ Wl, const float* __restrict__ Wr,
                                             const float* __restrict__ bias, float* OUT,
                                             int N, int relu) {
  __shared__ float As[64][36];    // [node][k] padded
  __shared__ float Ws[32][132];   // [k][h] transposed, padded
  int tid = threadIdx.x;
  int tx = tid & 15;              // h group: h0 = tx*8
  int ty = tid >> 4;              // node group: n0 = ty*4
  int rowBase = blockIdx.x * 64;
  float acc[4][8];
#pragma unroll
  for (int i = 0; i < 4; ++i)
#pragma unroll
    for (int j = 0; j < 8; ++j) acc[i][j] = 0.f;

  for (int c = 0; c < 8; ++c) {
    const float* S = (c < 4) ? A : X;
    const float* W = (c < 4) ? Wl : Wr;
    int kOff = (c & 3) * 32;
    __syncthreads();
    // stage A chunk: 64 rows x 32 k
#pragma unroll
    for (int n = 0; n < 2; ++n) {
      int idx = tid + n * 256;
      int r = idx >> 3, q = idx & 7;
      int gr = min(rowBase + r, N - 1);
      const float4 v = *(const float4*)(S + (size_t)gr * 128 + kOff + q * 4);
      *(float4*)(&As[r][q * 4]) = v;
    }
    // stage W chunk transposed: Ws[k][h] = W[h][kOff+k]
#pragma unroll
    for (int n = 0; n < 4; ++n) {
      int idx = tid + n * 256;
      int h = idx >> 3, q = idx & 7;
      const float4 v = *(const float4*)(W + (size_t)h * 128 + kOff + q * 4);
      Ws[q * 4 + 0][h] = v.x;
      Ws[q * 4 + 1][h] = v.y;
      Ws[q * 4 + 2][h] = v.z;
      Ws[q * 4 + 3][h] = v.w;
    }
    __syncthreads();
#pragma unroll
    for (int kk = 0; kk < 32; ++kk) {
      float a[4];
#pragma unroll
      for (int i = 0; i < 4; ++i) a[i] = As[ty * 4 + i][kk];
      const float4 w0 = *(const float4*)(&Ws[kk][tx * 8]);
      const float4 w1 = *(const float4*)(&Ws[kk][tx * 8 + 4]);
      float w[8] = {w0.x, w0.y, w0.z, w0.w, w1.x, w1.y, w1.z, w1.w};
#pragma unroll
      for (int i = 0; i < 4; ++i)
#pragma unroll
        for (int j = 0; j < 8; ++j) acc[i][j] += a[i] * w[j];
    }
  }
#pragma unroll
  for (int i = 0; i < 4; ++i) {
    int row = rowBase + ty * 4 + i;
    if (row < N) {
      int h0 = tx * 8;
      float4 r0, r1;
      r0.x = acc[i][0] + bias[h0 + 0];
      r0.y = acc[i][1] + bias[h0 + 1];
      r0.z = acc[i][2] + bias[h0 + 2];
      r0.w = acc[i][3] + bias[h0 + 3];
      r1.x = acc[i][4] + bias[h0 + 4];
      r1.y = acc[i][5] + bias[h0 + 5];
      r1.z = acc[i][6] + bias[h0 + 6];
      r1.w = acc[i][7] + bias[h0 + 7];
      if (relu) {
        r0.x = fmaxf(r0.x, 0.f); r0.y = fmaxf(r0.y, 0.f); r0.z = fmaxf(r0.z, 0.f); r0.w = fmaxf(r0.w, 0.f);
        r1.x = fmaxf(r1.x, 0.f); r1.y = fmaxf(r1.y, 0.f); r1.z = fmaxf(r1.z, 0.f); r1.w = fmaxf(r1.w, 0.f);
      }
      *(float4*)(OUT + (size_t)row * 128 + h0) = r0;
      *(float4*)(OUT + (size_t)row * 128 + h0 + 4) = r1;
    }
  }
}

// ---- global mean pool (batch is sorted) -----------------------------------

#define POOL_NODES 256
__global__ __launch_bounds__(128) void k_pool(const float* __restrict__ H, const int* __restrict__ batch,
                                              float* __restrict__ gsum, int* __restrict__ gcnt, int N) {
  int f = threadIdx.x;  // feature
  int start = blockIdx.x * POOL_NODES;
  int end = min(start + POOL_NODES, N);
  if (start >= N) return;
  float acc = 0.f;
  int curg = batch[start];
  int run = 0;
  for (int i = start; i < end; ++i) {
    int g = batch[i];
    if (g != curg) {
      atomicAdd(&gsum[curg * 128 + f], acc);
      if (f == 0) atomicAdd(&gcnt[curg], run);
      acc = 0.f;
      run = 0;
      curg = g;
    }
    acc += H[(size_t)i * 128 + f];
    run++;
  }
  atomicAdd(&gsum[curg * 128 + f], acc);
  if (f == 0) atomicAdd(&gcnt[curg], run);
}

// ---- classifier -----------------------------------------------------------

__global__ __launch_bounds__(128) void k_cls1(const float* __restrict__ gsum, const int* __restrict__ gcnt,
                                              const float* __restrict__ Wc1, const float* __restrict__ bc1,
                                              float* __restrict__ z) {
  int g = blockIdx.x;   // 64 graphs
  int h = threadIdx.x;  // 128 hidden
  float inv = 1.0f / (float)max(gcnt[g], 1);
  float s = 0.f;
  for (int f = 0; f < 128; ++f) s += gsum[g * 128 + f] * Wc1[h * 128 + f];
  z[g * 128 + h] = fmaxf(s * inv + bc1[h], 0.f);
}

__global__ __launch_bounds__(128) void k_cls2(const float* __restrict__ z, const float* __restrict__ Wc2,
                                              const float* __restrict__ bc2, float* __restrict__ out) {
  __shared__ float red[128];
  int g = blockIdx.x;
  int t = threadIdx.x;
  red[t] = z[g * 128 + t] * Wc2[t];
  __syncthreads();
  for (int d = 64; d > 0; d >>= 1) {
    if (t < d) red[t] += red[t + d];
    __syncthreads();
  }
  if (t == 0) out[g] = red[0] + bc2[0];
}

// ---------------------------------------------------------------------------

extern "C" void kernel_launch(void* const* d_in, const int* in_sizes, int n_in,
                              void* d_out, int out_size, void* d_ws, size_t ws_size,
                              hipStream_t stream) {
  const float* x   = (const float*)d_in[0];
  const int*   ei  = (const int*)d_in[1];
  const int*   bat = (const int*)d_in[2];
  const float* W1l = (const float*)d_in[3];
  const float* b1l = (const float*)d_in[4];
  const float* W1r = (const float*)d_in[5];
  const float* W2l = (const float*)d_in[6];
  const float* b2l = (const float*)d_in[7];
  const float* W2r = (const float*)d_in[8];
  const float* Wc1 = (const float*)d_in[9];
  const float* bc1 = (const float*)d_in[10];
  const float* Wc2 = (const float*)d_in[11];
  const float* bc2 = (const float*)d_in[12];
  float* out = (float*)d_out;

  int N = in_sizes[0] / 128;
  int E = in_sizes[1] / 2;
  int nScanBlk = (N + 1023) / 1024;  // 49 for N=50000; must be <= 256

  char* ws = (char*)d_ws;
  size_t o = 0;
  auto alloc = [&](size_t bytes) {
    char* p = ws + o;
    o += (bytes + 255) & ~(size_t)255;
    return p;
  };
  int*   cursor = (int*)alloc((size_t)N * 4);            // deg counter, then fill cursor
  int*   off    = (int*)alloc((size_t)(N + 1) * 4);
  int*   col    = (int*)alloc((size_t)E * 4);
  int*   bsum   = (int*)alloc(256 * 4);
  float* T      = (float*)alloc((size_t)N * 128 * 4);    // agg buffer; layer-2 out aliases it
  float* h1     = (float*)alloc((size_t)N * 128 * 4);
  float* gsum   = (float*)alloc(64 * 128 * 4 + 64 * 4);  // gsum + gcnt contiguous
  int*   gcnt   = (int*)(gsum + 64 * 128);
  float* z      = (float*)alloc(64 * 128 * 4);

  hipMemsetAsync(cursor, 0, (size_t)N * 4, stream);
  hipMemsetAsync(gsum, 0, 64 * 128 * 4 + 64 * 4, stream);

  k_deg<<<(E + 255) / 256, 256, 0, stream>>>(ei, cursor, E);
  k_scan_local<<<nScanBlk, 256, 0, stream>>>(cursor, off, bsum, N);
  k_scan_mid<<<1, 256, 0, stream>>>(bsum, off + N, nScanBlk);
  k_scan_add<<<nScanBlk, 256, 0, stream>>>(off, cursor, bsum, N);
  k_fill<<<(E + 255) / 256, 256, 0, stream>>>(ei, cursor, col, E);

  // layer 1
  k_agg<<<(N + 3) / 4, 256, 0, stream>>>(x, off, col, T, N);
  k_lin<<<(N + 63) / 64, 256, 0, stream>>>(T, x, W1l, W1r, b1l, h1, N, 1);
  // layer 2 (output aliases T; per-block row ownership makes this safe)
  k_agg<<<(N + 3) / 4, 256, 0, stream>>>(h1, off, col, T, N);
  k_lin<<<(N + 63) / 64, 256, 0, stream>>>(T, h1, W2l, W2r, b2l, T, N, 1);

  // pooling + classifier
  k_pool<<<(N + POOL_NODES - 1) / POOL_NODES, 128, 0, stream>>>(T, bat, gsum, gcnt, N);
  k_cls1<<<64, 128, 0, stream>>>(gsum, gcnt, Wc1, bc1, z);
  k_cls2<<<64, 128, 0, stream>>>(z, Wc2, bc2, out);
}